// Round 15
// baseline (292.586 us; speedup 1.0000x reference)
//
#include <hip/hip_runtime.h>

// k-th NN distance (k=32 -> 33rd smallest, self excluded), B=16384, D=128.
// R15: occupancy push on the verified R5 k_gram geometry — 64-col x 128-K
// dbuf panels (33KB LDS -> 4 blocks/CU, launch_bounds(256,4)), same 2x2
// wave layout / issue-early staging / single barrier / per-value predicated
// filter / no-atomic private segments. NT stores reverted (R14: +26MB WRITE,
// +12us). Fused prepstats + partial-sum thresh (R14-verified). Parallel
// fallback (R13-verified).

typedef unsigned short u16;
typedef unsigned int   u32;
typedef __attribute__((ext_vector_type(8))) u16    ushort8;
typedef __attribute__((ext_vector_type(8))) __bf16 bf16x8;
typedef __attribute__((ext_vector_type(4))) float  f32x4;
typedef __attribute__((ext_vector_type(4))) u32    u32x4;

#define NB   16384
#define ND   128
#define NSEG 32           // segments per row = 4 q * 2 wc * 4 lq
#define SCAP 12           // slots per segment (lambda~2.25)
#define NTH  33           // 33rd smallest
#define ZWH  (-2.62f)     // WH quantile z: p~0.0044 -> ~72 cands/row
#define NEGF (-3.0e38f)
#define POSF ( 3.0e38f)
#define NPB  64           // rows per prepstats block
#define NPBL 256          // prepstats grid

// ---- workspace layout (bytes), total ~31.5 MB ----
#define OFF_X    ((size_t)0)
#define OFF_NORM (OFF_X    + (size_t)NB * ND * 2)
#define OFF_TACC (OFF_NORM + (size_t)NB * 4)
#define OFF_PART (OFF_TACC + (size_t)NB * 4)
#define OFF_CNTS (OFF_PART + (size_t)NPBL * 130 * 4)
#define OFF_CAND (OFF_CNTS + (size_t)NB * NSEG * 4)

static __device__ __forceinline__ u16 f2bf(float f) {
  u32 u = __float_as_uint(f);
  u32 r = u + 0x7FFFu + ((u >> 16) & 1u);
  return (u16)(r >> 16);
}
static __device__ __forceinline__ float bf2f(u16 h) {
  return __uint_as_float(((u32)h) << 16);
}

#if defined(__has_builtin)
#if __has_builtin(__builtin_amdgcn_global_load_lds)
#define HAVE_GLDS 1
#endif
#endif

// Stage 16B/lane: LDS dest = wave-uniform base + lane*16 (linear).
static __device__ __forceinline__ void stage16(const u16* gsrc_lane,
                                               u16* lds_base, int l) {
#ifdef HAVE_GLDS
  __builtin_amdgcn_global_load_lds(
      (const __attribute__((address_space(1))) void*)gsrc_lane,
      (__attribute__((address_space(3))) void*)lds_base, 16, 0, 0);
#else
  *(ushort8*)(lds_base + l * 8) = *(const ushort8*)gsrc_lane;
#endif
}
// Stage 4B/lane (for the column-norm vector).
static __device__ __forceinline__ void stage4(const float* gsrc_lane,
                                              float* lds_base, int l) {
#ifdef HAVE_GLDS
  __builtin_amdgcn_global_load_lds(
      (const __attribute__((address_space(1))) void*)gsrc_lane,
      (__attribute__((address_space(3))) void*)lds_base, 4, 0, 0);
#else
  lds_base[l] = *gsrc_lane;
#endif
}

// ---------------- K1: fused bf16 convert + norms + stat partials ---------
__global__ void k_prepstats(const float* __restrict__ x, u16* __restrict__ X,
                            float* __restrict__ norms, float* __restrict__ partial) {
  __shared__ float xs[16][128];
  __shared__ float red1[256], red2[256];
  int t = threadIdx.x;
  int cg = t & 15;          // col-group: cols cg*8 .. cg*8+7
  int rs = t >> 4;          // row-sub 0..15
  int rbase = blockIdx.x * NPB;
  float cs[8] = {0.f, 0.f, 0.f, 0.f, 0.f, 0.f, 0.f, 0.f};
  float s1 = 0.f, s2 = 0.f;
#pragma unroll
  for (int rr = 0; rr < NPB / 16; ++rr) {
    int row = rbase + rs + rr * 16;
    const float* src = x + (size_t)row * ND + cg * 8;
    float4 a0 = *(const float4*)(src);
    float4 a1 = *(const float4*)(src + 4);
    float v[8] = {a0.x, a0.y, a0.z, a0.w, a1.x, a1.y, a1.z, a1.w};
    ushort8 pack;
    float ns = 0.f;
#pragma unroll
    for (int u = 0; u < 8; ++u) {
      u16 h = f2bf(v[u]);
      float b = bf2f(h);
      pack[u] = h;
      ns += b * b;
      cs[u] += b;
    }
    *(ushort8*)(X + (size_t)row * ND + cg * 8) = pack;
#pragma unroll
    for (int off = 1; off < 16; off <<= 1) ns += __shfl_xor(ns, off, 64);
    if (cg == 0) { norms[row] = ns; s1 += ns; s2 += ns * ns; }
  }
#pragma unroll
  for (int u = 0; u < 8; ++u) xs[rs][cg * 8 + u] = cs[u];
  red1[t] = s1; red2[t] = s2;
  __syncthreads();
  if (t < 128) {
    float a = 0.f;
    for (int r2 = 0; r2 < 16; ++r2) a += xs[r2][t];
    partial[(size_t)blockIdx.x * 130 + t] = a;
  }
  for (int st = 128; st > 0; st >>= 1) {
    if (t < st) { red1[t] += red1[t + st]; red2[t] += red2[t + st]; }
    __syncthreads();
  }
  if (t == 0) {
    partial[(size_t)blockIdx.x * 130 + 128] = red1[0];
    partial[(size_t)blockIdx.x * 130 + 129] = red2[0];
  }
}

// ---------------- K2: per-row threshold via Wilson-Hilferty chi^2 --------
__global__ void k_thresh(const u16* __restrict__ X, const float* __restrict__ norms,
                         const float* __restrict__ partial, float* __restrict__ tacc) {
  __shared__ float xb[128];
  __shared__ float ssum[2];
  int t = threadIdx.x;
  if (t < 128) {
    float a = 0.f;
    for (int b = 0; b < NPBL; ++b) a += partial[(size_t)b * 130 + t];
    xb[t] = a * (1.0f / NB);
  } else if (t == 128 || t == 129) {
    float a = 0.f;
    for (int b = 0; b < NPBL; ++b) a += partial[(size_t)b * 130 + t];
    ssum[t - 128] = a;
  }
  __syncthreads();
  int r = blockIdx.x * 256 + t;  // grid 64
  float n = norms[r];
  const u16* xr = X + (size_t)r * ND;
  float dot = 0.f;
#pragma unroll
  for (int c8 = 0; c8 < 16; ++c8) {
    ushort8 v = *(const ushort8*)(xr + c8 * 8);
#pragma unroll
    for (int j = 0; j < 8; ++j) dot += bf2f(v[j]) * xb[c8 * 8 + j];
  }
  float nbar = ssum[0] * (1.0f / NB);
  float Vn = fmaxf(ssum[1] * (1.0f / NB) - nbar * nbar, 0.f);
  float m = n + nbar - 2.f * dot;             // exact E_j[sq_rj]
  float v = Vn + 4.f * n * (nbar / ND);       // Var_j[sq_rj] model
  float nu = 2.f * m * m / v;
  float cc = v / (2.f * m);
  float a1 = 2.f / (9.f * nu);
  float inner = 1.f - a1 + ZWH * sqrtf(a1);
  float tsq = cc * nu * inner * inner * inner;
  tacc[r] = 0.5f * (n - tsq);   // val = acc - nc/2 >= tacc  <=>  sq <= tsq
}

// ---------------- K3: MFMA gram, 64-col dbuf panels, 4 blocks/CU ---------
// 512 blocks = 128 strips x 4 quarters (XCD-chunked). 4 waves as 2x2:
// wave (wr,wc) = 64 rows x 32 cols of the 128x64 iter tile. 64 iters.
// Issue-early dbuf staging, single end-of-iter barrier (R5 schedule).
__global__ __launch_bounds__(256, 4) void k_gram(
    const u16* __restrict__ X, const float* __restrict__ norms,
    const float* __restrict__ tacc, u32* __restrict__ counts,
    float* __restrict__ cands) {
  __shared__ u16 ldsA[2][16 * 512];            // 2 x 16KB (64 cols x 128 K)
  __shared__ __align__(16) float nchs[2][64];
  const int bid = blockIdx.x;
  const int logical = (bid & 7) * 64 + (bid >> 3);   // XCD-chunked, bijective
  const int q = logical >> 7, strip = logical & 127;
  const int r0 = strip * 128;
  const int t = threadIdx.x, w = t >> 6, l = t & 63;
  const int wr = w & 1, wc = w >> 1;
  const int lm = l & 15, lq = l >> 4;
  const int koff = lq * 8;

  // B fragments (owned rows) -> registers, loaded once.
  bf16x8 bfrag[4][4];  // [k][j]
#pragma unroll
  for (int k = 0; k < 4; ++k)
#pragma unroll
    for (int j = 0; j < 4; ++j)
      bfrag[k][j] = __builtin_bit_cast(bf16x8, *(const ushort8*)(
          X + (size_t)(r0 + (wr * 4 + j) * 16 + lm) * ND + k * 32 + koff));

  int rj[4]; float tj[4]; u32 cnt4[4]; u32 segb[4];
#pragma unroll
  for (int j = 0; j < 4; ++j) {
    rj[j] = r0 + (wr * 4 + j) * 16 + lm;
    tj[j] = tacc[rj[j]];
    cnt4[j] = 0;
    segb[j] = (u32)(rj[j] * NSEG + q * 8 + wc * 4 + lq) * SCAP;
  }

  // prologue: stage panel 0 into buffer 0 (16 groups; 4 per wave)
  {
    const int c0 = q * 4096;
#pragma unroll
    for (int s = 0; s < 4; ++s) {
      int g = w * 4 + s;                 // col-entity g&3, k-chunk g>>2
      stage16(X + (size_t)(c0 + (g & 3) * 16 + lm) * ND + (g >> 2) * 32 + koff,
              &ldsA[0][g * 512], l);
    }
    if (w == 0) stage4(norms + c0 + l, &nchs[0][0], l);
  }
  __syncthreads();

  for (int it = 0; it < 64; ++it) {
    const int cur = it & 1;
    const int c0 = q * 4096 + it * 64;
    // issue next-panel staging FIRST (into the other buffer)
    if (it + 1 < 64) {
      const int c1 = c0 + 64;
      u16* dstA = ldsA[cur ^ 1];
#pragma unroll
      for (int s = 0; s < 4; ++s) {
        int g = w * 4 + s;
        stage16(X + (size_t)(c1 + (g & 3) * 16 + lm) * ND + (g >> 2) * 32 + koff,
                &dstA[g * 512], l);
      }
      if (w == 0) stage4(norms + c1 + l, &nchs[cur ^ 1][0], l);
    }
    __builtin_amdgcn_sched_barrier(0);  // pin staging issue before compute

    f32x4 acc[2][4];
#pragma unroll
    for (int i = 0; i < 2; ++i)
#pragma unroll
      for (int j = 0; j < 4; ++j) acc[i][j] = (f32x4){0.f, 0.f, 0.f, 0.f};

    const u16* srcA = ldsA[cur];
#pragma unroll
    for (int k = 0; k < 4; ++k) {
      bf16x8 af[2];
#pragma unroll
      for (int i = 0; i < 2; ++i)
        af[i] = __builtin_bit_cast(bf16x8,
                 *(const ushort8*)(&srcA[(k * 4 + wc * 2 + i) * 512 + l * 8]));
#pragma unroll
      for (int i = 0; i < 2; ++i)
#pragma unroll
        for (int j = 0; j < 4; ++j)
          acc[i][j] = __builtin_amdgcn_mfma_f32_16x16x32_bf16(af[i], bfrag[k][j], acc[i][j], 0, 0, 0);
    }

    f32x4 nch4[2];
#pragma unroll
    for (int i = 0; i < 2; ++i) {
      nch4[i] = *(const f32x4*)(&nchs[cur][wc * 32 + i * 16 + lq * 4]);
      nch4[i] = nch4[i] * 0.5f;
    }

    // R5's verified per-value predicated filter
    const bool dg = ((u32)(c0 - r0) < 128u);
#pragma unroll
    for (int i = 0; i < 2; ++i) {
#pragma unroll
      for (int j = 0; j < 4; ++j) {
#pragma unroll
        for (int v = 0; v < 4; ++v) {
          float val = acc[i][j][v] - nch4[i][v];   // = x_c.x_r - n_c/2
          bool p = (val >= tj[j]);
          if (dg) p = p && ((c0 + wc * 32 + i * 16 + lq * 4 + v) != rj[j]);
          if (p) {
            u32 c = cnt4[j];
            if (c < SCAP) cands[segb[j] + c] = val;
            cnt4[j] = c + 1;   // count past cap -> overflow detect
          }
        }
      }
    }

    __syncthreads();  // drains vmcnt(0): next panel staged; cur readers done
  }
#pragma unroll
  for (int j = 0; j < 4; ++j)
    counts[rj[j] * NSEG + q * 8 + wc * 4 + lq] = cnt4[j];
}

// ---------------- K4: per-row exact 33rd smallest among candidates --------
__global__ void k_select(const u32* __restrict__ counts, const float* __restrict__ cands,
                         const float* __restrict__ norms, float* __restrict__ out) {
  int w = threadIdx.x >> 6, l = threadIdx.x & 63;
  int r = blockIdx.x * 4 + w;  // grid 4096
  u32 myc = (l < NSEG) ? counts[r * NSEG + l] : 0u;
  u32 tot = myc, mx = myc;
#pragma unroll
  for (int off = 1; off < 64; off <<= 1) {
    tot += __shfl_xor(tot, off, 64);
    u32 o = (u32)__shfl_xor((int)mx, off, 64);
    mx = mx > o ? mx : o;
  }
  if (tot < NTH || mx > SCAP) return;  // fallback kernel owns this row

  const float* base = cands + (size_t)r * (NSEG * SCAP);
  float v0, v1, v2, v3, v4, v5;
#define LOADV(e, dst)                                        \
  {                                                          \
    int f = l + 64 * e;                                      \
    int sg = f / SCAP, sl = f - sg * SCAP;                   \
    u32 c = (u32)__shfl((int)myc, sg, 64);                   \
    float x = base[f];                                       \
    dst = (sl < (int)c) ? x : NEGF;                          \
  }
  LOADV(0, v0) LOADV(1, v1) LOADV(2, v2) LOADV(3, v3) LOADV(4, v4) LOADV(5, v5)
#undef LOADV

  float last = NEGF;
  for (int e = 0; e < NTH; ++e) {  // bigger val = closer; extract-max x33
    float m = fmaxf(fmaxf(fmaxf(v0, v1), fmaxf(v2, v3)), fmaxf(v4, v5));
#pragma unroll
    for (int off = 1; off < 64; off <<= 1) m = fmaxf(m, __shfl_xor(m, off, 64));
    bool mine = (v0 == m) || (v1 == m) || (v2 == m) || (v3 == m) || (v4 == m) || (v5 == m);
    unsigned long long bal = __ballot(mine);
    int owner = __ffsll(bal) - 1;
    if (l == owner) {
      if      (v0 == m) v0 = NEGF;
      else if (v1 == m) v1 = NEGF;
      else if (v2 == m) v2 = NEGF;
      else if (v3 == m) v3 = NEGF;
      else if (v4 == m) v4 = NEGF;
      else              v5 = NEGF;
    }
    last = m;
  }
  out[r] = sqrtf(fmaxf(norms[r] - 2.f * last, 0.f));  // sq = n_r - 2*val
}

// ---------------- K5: exact brute-force fallback (expected ~0 rows) -------
__global__ void k_fallback(const u32* __restrict__ counts, const u16* __restrict__ X,
                           const float* __restrict__ norms, float* __restrict__ out) {
  __shared__ float sq[NB];     // 64 KB
  __shared__ float xr[ND];
  __shared__ float rmin[256];
  __shared__ int   ridx[256];
  __shared__ float tmin[256];
  __shared__ int   tidx[256];
  __shared__ int   nbad;
  __shared__ int   badlist[256];
  int t = threadIdx.x;
  if (t == 0) nbad = 0;
  __syncthreads();
  int r = blockIdx.x * 256 + t;   // grid 64: covers NB exactly
  u32 tot = 0, mx = 0;
#pragma unroll
  for (int s4 = 0; s4 < 8; ++s4) {
    u32x4 c = *(const u32x4*)(counts + (size_t)r * NSEG + s4 * 4);
#pragma unroll
    for (int u = 0; u < 4; ++u) { tot += c[u]; mx = c[u] > mx ? c[u] : mx; }
  }
  if (tot < NTH || mx > SCAP) { int p = atomicAdd(&nbad, 1); badlist[p] = r; }
  __syncthreads();
  int nb = nbad;
  for (int ii = 0; ii < nb; ++ii) {
    int rr = badlist[ii];
    if (t < 128) xr[t] = bf2f(X[(size_t)rr * ND + t]);
    __syncthreads();
    float n_r = norms[rr];
    for (int jj = 0; jj < 64; ++jj) {
      int j = t + 256 * jj;
      const u16* xj = X + (size_t)j * ND;
      float dot = 0.f;
#pragma unroll
      for (int c8 = 0; c8 < 16; ++c8) {
        ushort8 vv = *(const ushort8*)(xj + c8 * 8);
#pragma unroll
        for (int u = 0; u < 8; ++u) dot += bf2f(vv[u]) * xr[c8 * 8 + u];
      }
      sq[j] = (j == rr) ? POSF : fmaxf(n_r + norms[j] - 2.f * dot, 0.f);
    }
    __syncthreads();
    {
      float lmv = POSF; int lix = -1;
      for (int jj = 0; jj < 64; ++jj) {
        int j = t + 256 * jj;
        float s = sq[j];
        if (s < lmv) { lmv = s; lix = j; }
      }
      rmin[t] = lmv; ridx[t] = lix;
    }
    __syncthreads();
    float last = 0.f;
    for (int e = 0; e < NTH; ++e) {
      tmin[t] = rmin[t]; tidx[t] = ridx[t];
      __syncthreads();
      for (int s = 128; s > 0; s >>= 1) {
        if (t < s && tmin[t + s] < tmin[t]) { tmin[t] = tmin[t + s]; tidx[t] = tidx[t + s]; }
        __syncthreads();
      }
      float gm = tmin[0]; int gi = tidx[0];
      last = gm;
      __syncthreads();
      if (t == (gi & 255)) {         // owner clears and rescans its stripe
        sq[gi] = POSF;
        float lmv = POSF; int lix = -1;
        for (int jj = 0; jj < 64; ++jj) {
          int j = t + 256 * jj;
          float s = sq[j];
          if (s < lmv) { lmv = s; lix = j; }
        }
        rmin[t] = lmv; ridx[t] = lix;
      }
      __syncthreads();
    }
    if (t == 0) out[rr] = sqrtf(fmaxf(last, 0.f));
    __syncthreads();
  }
}

extern "C" void kernel_launch(void* const* d_in, const int* in_sizes, int n_in,
                              void* d_out, int out_size, void* d_ws, size_t ws_size,
                              hipStream_t stream) {
  const float* x = (const float*)d_in[0];
  float* out = (float*)d_out;
  char* ws = (char*)d_ws;
  u16*   X     = (u16*)  (ws + OFF_X);
  float* norms = (float*)(ws + OFF_NORM);
  float* tacc  = (float*)(ws + OFF_TACC);
  float* part  = (float*)(ws + OFF_PART);
  u32*   cnts  = (u32*)  (ws + OFF_CNTS);
  float* cands = (float*)(ws + OFF_CAND);

  k_prepstats<<<NPBL, 256, 0, stream>>>(x, X, norms, part);
  k_thresh   <<<64,   256, 0, stream>>>(X, norms, part, tacc);
  k_gram     <<<512,  256, 0, stream>>>(X, norms, tacc, cnts, cands);
  k_select   <<<4096, 256, 0, stream>>>(cnts, cands, norms, out);
  k_fallback <<<64,   256, 0, stream>>>(cnts, X, norms, out);
}

// Round 18
// 181.544 us; speedup vs baseline: 1.6117x; 1.6117x over previous
//
#include <hip/hip_runtime.h>

// k-th NN distance (k=32 -> 33rd smallest, self excluded), B=16384, D=128.
// R16 second resubmit (two consecutive container infra failures R16/R17,
// no GPU signal either time; identical source): occupancy via 8-wave
// (512-thread) blocks on R5's verified k_gram geometry — same 128-col dbuf
// panels, same 32 iters, same (q,wc,lq) segment partition (lambda=2.25,
// SCAP=12, count-stats identical to the verified 144us kernel). 8 waves =
// 4 row-groups x 2 col-halves (wave 32rx64c, j=2). 2 blocks/CU x 8 waves =
// 4 waves/SIMD (R5 had 2). R15 lesson: occupancy was grid/dispatch-capped,
// not LDS-capped. Fused prepstats + partial thresh (R14), parallel
// fallback (R13).

typedef unsigned short u16;
typedef unsigned int   u32;
typedef __attribute__((ext_vector_type(8))) u16    ushort8;
typedef __attribute__((ext_vector_type(8))) __bf16 bf16x8;
typedef __attribute__((ext_vector_type(4))) float  f32x4;
typedef __attribute__((ext_vector_type(4))) u32    u32x4;

#define NB   16384
#define ND   128
#define NSEG 32           // segments per row = 4 q * 2 wc * 4 lq
#define SCAP 12           // slots per segment (lambda~2.25)
#define NTH  33           // 33rd smallest
#define ZWH  (-2.62f)     // WH quantile z: p~0.0044 -> ~72 cands/row
#define NEGF (-3.0e38f)
#define POSF ( 3.0e38f)
#define NPB  64           // rows per prepstats block
#define NPBL 256          // prepstats grid

// ---- workspace layout (bytes), total ~31.5 MB ----
#define OFF_X    ((size_t)0)
#define OFF_NORM (OFF_X    + (size_t)NB * ND * 2)
#define OFF_TACC (OFF_NORM + (size_t)NB * 4)
#define OFF_PART (OFF_TACC + (size_t)NB * 4)
#define OFF_CNTS (OFF_PART + (size_t)NPBL * 130 * 4)
#define OFF_CAND (OFF_CNTS + (size_t)NB * NSEG * 4)

static __device__ __forceinline__ u16 f2bf(float f) {
  u32 u = __float_as_uint(f);
  u32 r = u + 0x7FFFu + ((u >> 16) & 1u);
  return (u16)(r >> 16);
}
static __device__ __forceinline__ float bf2f(u16 h) {
  return __uint_as_float(((u32)h) << 16);
}

#if defined(__has_builtin)
#if __has_builtin(__builtin_amdgcn_global_load_lds)
#define HAVE_GLDS 1
#endif
#endif

// Stage 16B/lane: LDS dest = wave-uniform base + lane*16 (linear).
static __device__ __forceinline__ void stage16(const u16* gsrc_lane,
                                               u16* lds_base, int l) {
#ifdef HAVE_GLDS
  __builtin_amdgcn_global_load_lds(
      (const __attribute__((address_space(1))) void*)gsrc_lane,
      (__attribute__((address_space(3))) void*)lds_base, 16, 0, 0);
#else
  *(ushort8*)(lds_base + l * 8) = *(const ushort8*)gsrc_lane;
#endif
}
// Stage 4B/lane (for the column-norm vector).
static __device__ __forceinline__ void stage4(const float* gsrc_lane,
                                              float* lds_base, int l) {
#ifdef HAVE_GLDS
  __builtin_amdgcn_global_load_lds(
      (const __attribute__((address_space(1))) void*)gsrc_lane,
      (__attribute__((address_space(3))) void*)lds_base, 4, 0, 0);
#else
  lds_base[l] = *gsrc_lane;
#endif
}

// ---------------- K1: fused bf16 convert + norms + stat partials ---------
__global__ void k_prepstats(const float* __restrict__ x, u16* __restrict__ X,
                            float* __restrict__ norms, float* __restrict__ partial) {
  __shared__ float xs[16][128];
  __shared__ float red1[256], red2[256];
  int t = threadIdx.x;
  int cg = t & 15;          // col-group: cols cg*8 .. cg*8+7
  int rs = t >> 4;          // row-sub 0..15
  int rbase = blockIdx.x * NPB;
  float cs[8] = {0.f, 0.f, 0.f, 0.f, 0.f, 0.f, 0.f, 0.f};
  float s1 = 0.f, s2 = 0.f;
#pragma unroll
  for (int rr = 0; rr < NPB / 16; ++rr) {
    int row = rbase + rs + rr * 16;
    const float* src = x + (size_t)row * ND + cg * 8;
    float4 a0 = *(const float4*)(src);
    float4 a1 = *(const float4*)(src + 4);
    float v[8] = {a0.x, a0.y, a0.z, a0.w, a1.x, a1.y, a1.z, a1.w};
    ushort8 pack;
    float ns = 0.f;
#pragma unroll
    for (int u = 0; u < 8; ++u) {
      u16 h = f2bf(v[u]);
      float b = bf2f(h);
      pack[u] = h;
      ns += b * b;
      cs[u] += b;
    }
    *(ushort8*)(X + (size_t)row * ND + cg * 8) = pack;
#pragma unroll
    for (int off = 1; off < 16; off <<= 1) ns += __shfl_xor(ns, off, 64);
    if (cg == 0) { norms[row] = ns; s1 += ns; s2 += ns * ns; }
  }
#pragma unroll
  for (int u = 0; u < 8; ++u) xs[rs][cg * 8 + u] = cs[u];
  red1[t] = s1; red2[t] = s2;
  __syncthreads();
  if (t < 128) {
    float a = 0.f;
    for (int r2 = 0; r2 < 16; ++r2) a += xs[r2][t];
    partial[(size_t)blockIdx.x * 130 + t] = a;
  }
  for (int st = 128; st > 0; st >>= 1) {
    if (t < st) { red1[t] += red1[t + st]; red2[t] += red2[t + st]; }
    __syncthreads();
  }
  if (t == 0) {
    partial[(size_t)blockIdx.x * 130 + 128] = red1[0];
    partial[(size_t)blockIdx.x * 130 + 129] = red2[0];
  }
}

// ---------------- K2: per-row threshold via Wilson-Hilferty chi^2 --------
__global__ void k_thresh(const u16* __restrict__ X, const float* __restrict__ norms,
                         const float* __restrict__ partial, float* __restrict__ tacc) {
  __shared__ float xb[128];
  __shared__ float ssum[2];
  int t = threadIdx.x;
  if (t < 128) {
    float a = 0.f;
    for (int b = 0; b < NPBL; ++b) a += partial[(size_t)b * 130 + t];
    xb[t] = a * (1.0f / NB);
  } else if (t == 128 || t == 129) {
    float a = 0.f;
    for (int b = 0; b < NPBL; ++b) a += partial[(size_t)b * 130 + t];
    ssum[t - 128] = a;
  }
  __syncthreads();
  int r = blockIdx.x * 256 + t;  // grid 64
  float n = norms[r];
  const u16* xr = X + (size_t)r * ND;
  float dot = 0.f;
#pragma unroll
  for (int c8 = 0; c8 < 16; ++c8) {
    ushort8 v = *(const ushort8*)(xr + c8 * 8);
#pragma unroll
    for (int j = 0; j < 8; ++j) dot += bf2f(v[j]) * xb[c8 * 8 + j];
  }
  float nbar = ssum[0] * (1.0f / NB);
  float Vn = fmaxf(ssum[1] * (1.0f / NB) - nbar * nbar, 0.f);
  float m = n + nbar - 2.f * dot;             // exact E_j[sq_rj]
  float v = Vn + 4.f * n * (nbar / ND);       // Var_j[sq_rj] model
  float nu = 2.f * m * m / v;
  float cc = v / (2.f * m);
  float a1 = 2.f / (9.f * nu);
  float inner = 1.f - a1 + ZWH * sqrtf(a1);
  float tsq = cc * nu * inner * inner * inner;
  tacc[r] = 0.5f * (n - tsq);   // val = acc - nc/2 >= tacc  <=>  sq <= tsq
}

// ---------------- K3: MFMA gram, 8-wave blocks on R5 geometry ------------
// 512 blocks = 128 strips x 4 quarters (XCD-chunked). 512 thr = 8 waves:
// (wr=w>>1 in [0,4)) x (wc=w&1 in [0,2)); wave = 32 rows x 64 cols of the
// 128x128 iter tile. Same panels / staging / barrier / filter as R5.
__global__ __launch_bounds__(512, 4) void k_gram(
    const u16* __restrict__ X, const float* __restrict__ norms,
    const float* __restrict__ tacc, u32* __restrict__ counts,
    float* __restrict__ cands) {
  __shared__ u16 ldsA[2][32 * 512];            // 2 x 32KB
  __shared__ __align__(16) float nchs[2][128];
  const int bid = blockIdx.x;
  const int logical = (bid & 7) * 64 + (bid >> 3);   // XCD-chunked, bijective
  const int q = logical >> 7, strip = logical & 127;
  const int r0 = strip * 128;
  const int t = threadIdx.x, w = t >> 6, l = t & 63;
  const int wr = w >> 1, wc = w & 1;
  const int lm = l & 15, lq = l >> 4;
  const int koff = lq * 8;

  // B fragments (wave's 32 rows) -> registers, loaded once.
  bf16x8 bfrag[4][2];  // [k][j]
#pragma unroll
  for (int k = 0; k < 4; ++k)
#pragma unroll
    for (int j = 0; j < 2; ++j)
      bfrag[k][j] = __builtin_bit_cast(bf16x8, *(const ushort8*)(
          X + (size_t)(r0 + wr * 32 + j * 16 + lm) * ND + k * 32 + koff));

  int rj[2]; float tj[2]; u32 cnt2[2]; u32 segb[2];
#pragma unroll
  for (int j = 0; j < 2; ++j) {
    rj[j] = r0 + wr * 32 + j * 16 + lm;
    tj[j] = tacc[rj[j]];
    cnt2[j] = 0;
    segb[j] = (u32)(rj[j] * NSEG + q * 8 + wc * 4 + lq) * SCAP;
  }

  // prologue: stage tile 0 into buffer 0 (32 groups; 4 per wave)
  {
    const int c0 = q * 4096;
#pragma unroll
    for (int s = 0; s < 4; ++s) {
      int g = w * 4 + s;                 // e16 = g&7, k-chunk = g>>3
      stage16(X + (size_t)(c0 + (g & 7) * 16 + lm) * ND + (g >> 3) * 32 + koff,
              &ldsA[0][g * 512], l);
    }
    if (w < 2) stage4(norms + c0 + w * 64 + l, &nchs[0][w * 64], l);
  }
  __syncthreads();

  for (int it = 0; it < 32; ++it) {
    const int cur = it & 1;
    const int c0 = q * 4096 + it * 128;
    // issue next-tile staging FIRST (into the other buffer)
    if (it + 1 < 32) {
      const int c1 = c0 + 128;
      u16* dstA = ldsA[cur ^ 1];
#pragma unroll
      for (int s = 0; s < 4; ++s) {
        int g = w * 4 + s;
        stage16(X + (size_t)(c1 + (g & 7) * 16 + lm) * ND + (g >> 3) * 32 + koff,
                &dstA[g * 512], l);
      }
      if (w < 2) stage4(norms + c1 + w * 64 + l, &nchs[cur ^ 1][w * 64], l);
    }
    __builtin_amdgcn_sched_barrier(0);  // pin staging issue before compute

    f32x4 acc[4][2];
#pragma unroll
    for (int i = 0; i < 4; ++i)
#pragma unroll
      for (int j = 0; j < 2; ++j) acc[i][j] = (f32x4){0.f, 0.f, 0.f, 0.f};

    const u16* srcA = ldsA[cur];
#pragma unroll
    for (int k = 0; k < 4; ++k) {
      bf16x8 af[4];
#pragma unroll
      for (int i = 0; i < 4; ++i)
        af[i] = __builtin_bit_cast(bf16x8,
                 *(const ushort8*)(&srcA[(k * 8 + wc * 4 + i) * 512 + l * 8]));
#pragma unroll
      for (int i = 0; i < 4; ++i)
#pragma unroll
        for (int j = 0; j < 2; ++j)
          acc[i][j] = __builtin_amdgcn_mfma_f32_16x16x32_bf16(af[i], bfrag[k][j], acc[i][j], 0, 0, 0);
    }

    f32x4 nch4[4];
#pragma unroll
    for (int i = 0; i < 4; ++i) {
      nch4[i] = *(const f32x4*)(&nchs[cur][wc * 64 + i * 16 + lq * 4]);
      nch4[i] = nch4[i] * 0.5f;
    }

    // R5's verified per-value predicated filter (same column partition)
    const bool dg = (c0 == r0);
#pragma unroll
    for (int i = 0; i < 4; ++i) {
#pragma unroll
      for (int j = 0; j < 2; ++j) {
#pragma unroll
        for (int v = 0; v < 4; ++v) {
          float val = acc[i][j][v] - nch4[i][v];   // = x_c.x_r - n_c/2
          bool p = (val >= tj[j]);
          if (dg) p = p && ((c0 + wc * 64 + i * 16 + lq * 4 + v) != rj[j]);
          if (p) {
            u32 c = cnt2[j];
            if (c < SCAP) cands[segb[j] + c] = val;
            cnt2[j] = c + 1;   // count past cap -> overflow detect
          }
        }
      }
    }

    __syncthreads();  // drains vmcnt(0): next tile staged; cur readers done
  }
#pragma unroll
  for (int j = 0; j < 2; ++j)
    counts[rj[j] * NSEG + q * 8 + wc * 4 + lq] = cnt2[j];
}

// ---------------- K4: per-row exact 33rd smallest among candidates --------
__global__ void k_select(const u32* __restrict__ counts, const float* __restrict__ cands,
                         const float* __restrict__ norms, float* __restrict__ out) {
  int w = threadIdx.x >> 6, l = threadIdx.x & 63;
  int r = blockIdx.x * 4 + w;  // grid 4096
  u32 myc = (l < NSEG) ? counts[r * NSEG + l] : 0u;
  u32 tot = myc, mx = myc;
#pragma unroll
  for (int off = 1; off < 64; off <<= 1) {
    tot += __shfl_xor(tot, off, 64);
    u32 o = (u32)__shfl_xor((int)mx, off, 64);
    mx = mx > o ? mx : o;
  }
  if (tot < NTH || mx > SCAP) return;  // fallback kernel owns this row

  const float* base = cands + (size_t)r * (NSEG * SCAP);
  float v0, v1, v2, v3, v4, v5;
#define LOADV(e, dst)                                        \
  {                                                          \
    int f = l + 64 * e;                                      \
    int sg = f / SCAP, sl = f - sg * SCAP;                   \
    u32 c = (u32)__shfl((int)myc, sg, 64);                   \
    float x = base[f];                                       \
    dst = (sl < (int)c) ? x : NEGF;                          \
  }
  LOADV(0, v0) LOADV(1, v1) LOADV(2, v2) LOADV(3, v3) LOADV(4, v4) LOADV(5, v5)
#undef LOADV

  float last = NEGF;
  for (int e = 0; e < NTH; ++e) {  // bigger val = closer; extract-max x33
    float m = fmaxf(fmaxf(fmaxf(v0, v1), fmaxf(v2, v3)), fmaxf(v4, v5));
#pragma unroll
    for (int off = 1; off < 64; off <<= 1) m = fmaxf(m, __shfl_xor(m, off, 64));
    bool mine = (v0 == m) || (v1 == m) || (v2 == m) || (v3 == m) || (v4 == m) || (v5 == m);
    unsigned long long bal = __ballot(mine);
    int owner = __ffsll(bal) - 1;
    if (l == owner) {
      if      (v0 == m) v0 = NEGF;
      else if (v1 == m) v1 = NEGF;
      else if (v2 == m) v2 = NEGF;
      else if (v3 == m) v3 = NEGF;
      else if (v4 == m) v4 = NEGF;
      else              v5 = NEGF;
    }
    last = m;
  }
  out[r] = sqrtf(fmaxf(norms[r] - 2.f * last, 0.f));  // sq = n_r - 2*val
}

// ---------------- K5: exact brute-force fallback (expected ~0 rows) -------
__global__ void k_fallback(const u32* __restrict__ counts, const u16* __restrict__ X,
                           const float* __restrict__ norms, float* __restrict__ out) {
  __shared__ float sq[NB];     // 64 KB
  __shared__ float xr[ND];
  __shared__ float rmin[256];
  __shared__ int   ridx[256];
  __shared__ float tmin[256];
  __shared__ int   tidx[256];
  __shared__ int   nbad;
  __shared__ int   badlist[256];
  int t = threadIdx.x;
  if (t == 0) nbad = 0;
  __syncthreads();
  int r = blockIdx.x * 256 + t;   // grid 64: covers NB exactly
  u32 tot = 0, mx = 0;
#pragma unroll
  for (int s4 = 0; s4 < 8; ++s4) {
    u32x4 c = *(const u32x4*)(counts + (size_t)r * NSEG + s4 * 4);
#pragma unroll
    for (int u = 0; u < 4; ++u) { tot += c[u]; mx = c[u] > mx ? c[u] : mx; }
  }
  if (tot < NTH || mx > SCAP) { int p = atomicAdd(&nbad, 1); badlist[p] = r; }
  __syncthreads();
  int nb = nbad;
  for (int ii = 0; ii < nb; ++ii) {
    int rr = badlist[ii];
    if (t < 128) xr[t] = bf2f(X[(size_t)rr * ND + t]);
    __syncthreads();
    float n_r = norms[rr];
    for (int jj = 0; jj < 64; ++jj) {
      int j = t + 256 * jj;
      const u16* xj = X + (size_t)j * ND;
      float dot = 0.f;
#pragma unroll
      for (int c8 = 0; c8 < 16; ++c8) {
        ushort8 vv = *(const ushort8*)(xj + c8 * 8);
#pragma unroll
        for (int u = 0; u < 8; ++u) dot += bf2f(vv[u]) * xr[c8 * 8 + u];
      }
      sq[j] = (j == rr) ? POSF : fmaxf(n_r + norms[j] - 2.f * dot, 0.f);
    }
    __syncthreads();
    {
      float lmv = POSF; int lix = -1;
      for (int jj = 0; jj < 64; ++jj) {
        int j = t + 256 * jj;
        float s = sq[j];
        if (s < lmv) { lmv = s; lix = j; }
      }
      rmin[t] = lmv; ridx[t] = lix;
    }
    __syncthreads();
    float last = 0.f;
    for (int e = 0; e < NTH; ++e) {
      tmin[t] = rmin[t]; tidx[t] = ridx[t];
      __syncthreads();
      for (int s = 128; s > 0; s >>= 1) {
        if (t < s && tmin[t + s] < tmin[t]) { tmin[t] = tmin[t + s]; tidx[t] = tidx[t + s]; }
        __syncthreads();
      }
      float gm = tmin[0]; int gi = tidx[0];
      last = gm;
      __syncthreads();
      if (t == (gi & 255)) {         // owner clears and rescans its stripe
        sq[gi] = POSF;
        float lmv = POSF; int lix = -1;
        for (int jj = 0; jj < 64; ++jj) {
          int j = t + 256 * jj;
          float s = sq[j];
          if (s < lmv) { lmv = s; lix = j; }
        }
        rmin[t] = lmv; ridx[t] = lix;
      }
      __syncthreads();
    }
    if (t == 0) out[rr] = sqrtf(fmaxf(last, 0.f));
    __syncthreads();
  }
}

extern "C" void kernel_launch(void* const* d_in, const int* in_sizes, int n_in,
                              void* d_out, int out_size, void* d_ws, size_t ws_size,
                              hipStream_t stream) {
  const float* x = (const float*)d_in[0];
  float* out = (float*)d_out;
  char* ws = (char*)d_ws;
  u16*   X     = (u16*)  (ws + OFF_X);
  float* norms = (float*)(ws + OFF_NORM);
  float* tacc  = (float*)(ws + OFF_TACC);
  float* part  = (float*)(ws + OFF_PART);
  u32*   cnts  = (u32*)  (ws + OFF_CNTS);
  float* cands = (float*)(ws + OFF_CAND);

  k_prepstats<<<NPBL, 256, 0, stream>>>(x, X, norms, part);
  k_thresh   <<<64,   256, 0, stream>>>(X, norms, part, tacc);
  k_gram     <<<512,  512, 0, stream>>>(X, norms, tacc, cnts, cands);
  k_select   <<<4096, 256, 0, stream>>>(cnts, cands, norms, out);
  k_fallback <<<64,   256, 0, stream>>>(cnts, X, norms, out);
}